// Round 2
// baseline (703.972 us; speedup 1.0000x reference)
//
#include <hip/hip_runtime.h>
#include <stdint.h>

#define N_NODES 100000
#define N_EDGES 1600000
#define FDIM 128
#define NREL 50
#define BN_EPS 1e-3f
#define N_PAD 100096
#define SCAN_B 1024
#define NBUCK 782          // ceil(N_NODES / 128)

typedef short short8_t __attribute__((ext_vector_type(8)));
typedef float f32x4_t __attribute__((ext_vector_type(4)));

__device__ __forceinline__ uint32_t f2bf(float f) {
    union { float f; uint32_t u; } v; v.f = f;
    uint32_t u = v.u;
    return (u + 0x7FFFu + ((u >> 16) & 1u)) >> 16;   // RNE, inputs finite
}
__device__ __forceinline__ float bflo(uint32_t p) {
    union { uint32_t u; float f; } v; v.u = p << 16; return v.f;
}
__device__ __forceinline__ float bfhi(uint32_t p) {
    union { uint32_t u; float f; } v; v.u = p & 0xFFFF0000u; return v.f;
}

// ---- prep: BN affine params, 1/(relc+1), W^T cast to bf16 ----
__global__ void prep_kernel(const float* __restrict__ gamma, const float* __restrict__ beta,
                            const float* __restrict__ mean, const float* __restrict__ var,
                            const float* __restrict__ relc, const float* __restrict__ W,
                            float* __restrict__ scale, float* __restrict__ shift,
                            float* __restrict__ rel_inv, uint16_t* __restrict__ WT) {
    int t = threadIdx.x;
    if (t < FDIM) {
        float s = gamma[t] * rsqrtf(var[t] + BN_EPS);
        scale[t] = s;
        shift[t] = beta[t] - mean[t] * s;
    }
    if (t < NREL) rel_inv[t] = 1.0f / (relc[t] + 1.0f);
    for (int idx = t; idx < FDIM * FDIM; idx += blockDim.x) {
        int f = idx >> 7, k = idx & 127;
        WT[idx] = (uint16_t)f2bf(W[k * FDIM + f]);   // WT[f][k]
    }
}

// ---- h = BN(x), stored bf16 ----
__global__ void h_kernel(const float* __restrict__ x, const float* __restrict__ scale,
                         const float* __restrict__ shift, uint2* __restrict__ h) {
    int i4 = blockIdx.x * blockDim.x + threadIdx.x;      // 0 .. N*32-1
    if (i4 >= N_NODES * 32) return;
    int cg = (i4 & 31) * 4;
    float4 xv = ((const float4*)x)[i4];
    float4 sc = *(const float4*)(scale + cg);
    float4 sh = *(const float4*)(shift + cg);
    uint2 o;
    o.x = f2bf(xv.x * sc.x + sh.x) | (f2bf(xv.y * sc.y + sh.y) << 16);
    o.y = f2bf(xv.z * sc.z + sh.z) | (f2bf(xv.w * sc.w + sh.w) << 16);
    h[i4] = o;
}

// ---- CSR build: histogram over rows only ----
__global__ void hist_kernel(const int* __restrict__ rows, int* __restrict__ counts) {
    int e = blockIdx.x * blockDim.x + threadIdx.x;
    if (e < N_EDGES) atomicAdd(&counts[rows[e]], 1);
}

__global__ void scan1_kernel(const int* __restrict__ counts, int* __restrict__ bsum) {
    __shared__ int sm[SCAN_B];
    int t = threadIdx.x;
    int i = blockIdx.x * SCAN_B + t;
    sm[t] = (i < N_NODES) ? counts[i] : 0;
    __syncthreads();
    for (int s = SCAN_B / 2; s > 0; s >>= 1) {
        if (t < s) sm[t] += sm[t + s];
        __syncthreads();
    }
    if (t == 0) bsum[blockIdx.x] = sm[0];
}

__global__ void scan2_kernel(const int* __restrict__ bsum, int* __restrict__ boff, int nb,
                             int* __restrict__ row_start) {
    if (threadIdx.x == 0) {
        int acc = 0;
        for (int b = 0; b < nb; ++b) { boff[b] = acc; acc += bsum[b]; }
        row_start[N_NODES] = acc;   // sentinel: == N_EDGES
    }
}

__global__ void scan3_kernel(const int* __restrict__ counts, const int* __restrict__ boff,
                             int* __restrict__ row_start, int* __restrict__ bcursor) {
    __shared__ int sm[SCAN_B];
    int t = threadIdx.x;
    int i = blockIdx.x * SCAN_B + t;
    int v = (i < N_NODES) ? counts[i] : 0;
    sm[t] = v;
    __syncthreads();
    for (int off = 1; off < SCAN_B; off <<= 1) {
        int xv = 0;
        if (t >= off) xv = sm[t - off];
        __syncthreads();
        sm[t] += xv;
        __syncthreads();
    }
    if (i < N_NODES) {
        int ex = boff[blockIdx.x] + sm[t] - v;   // exclusive scan
        row_start[i] = ex;
        if ((i & 127) == 0) bcursor[i >> 7] = ex;   // bucket base = row_start[b*128]
    }
}

// ---- pass A: partition edges into 128-row buckets. Bucket cursors advance
// monotonically -> active write window ~782 lines -> full-line coalescing. ----
__global__ void partition_kernel(const int* __restrict__ rows, const int* __restrict__ cols,
                                 const float* __restrict__ vals, const int* __restrict__ rels,
                                 const float* __restrict__ rel_inv, int* __restrict__ bcursor,
                                 uint2* __restrict__ staging) {
    int e = blockIdx.x * blockDim.x + threadIdx.x;
    if (e < N_EDGES) {
        int r = rows[e];
        float w = vals[e] * rel_inv[rels[e]];
        int p = atomicAdd(&bcursor[r >> 7], 1);
        uint2 s;
        s.x = (uint32_t)cols[e] | ((uint32_t)(r & 127) << 20);  // col<2^17, rowlocal<128
        s.y = __float_as_uint(w);
        staging[p] = s;
    }
}

// ---- pass B: one block per bucket; LDS row cursors; final writes confined
// to a ~16KB CSR window -> L2-coalesced. ----
__global__ __launch_bounds__(256) void bucket_kernel(
        const uint2* __restrict__ staging, const int* __restrict__ row_start,
        uint2* __restrict__ scolw) {
    __shared__ int lcur[128];
    int b = blockIdx.x;
    int r0 = b << 7;
    int nrows = min(128, N_NODES - r0);
    int t = threadIdx.x;
    if (t < nrows) lcur[t] = row_start[r0 + t];
    __syncthreads();
    int e0 = row_start[r0];
    int e1 = row_start[min(r0 + 128, N_NODES)];   // sentinel gives E for last bucket
    for (int e = e0 + t; e < e1; e += 256) {
        uint2 s = staging[e];
        int rl = (s.x >> 20) & 127;
        int p = atomicAdd(&lcur[rl], 1);
        uint2 o; o.x = s.x & 0xFFFFF; o.y = s.y;
        scolw[p] = o;
    }
}

// ---- pull-mode SpMM + diag: pre[i] = sum w_e h[col_e] + (ck_i+1) h[i] ----
__global__ __launch_bounds__(256) void spmm_kernel(
        const uint32_t* __restrict__ h, const int* __restrict__ row_start,
        const uint2* __restrict__ scolw, const float* __restrict__ ck,
        uint32_t* __restrict__ pre) {
    int row = blockIdx.x * 4 + (threadIdx.x >> 6);
    int lane = threadIdx.x & 63;
    uint32_t p = h[(size_t)row * 64 + lane];
    float coef = ck[row] + 1.0f;
    float ax = coef * bflo(p);
    float ay = coef * bfhi(p);
    int e0 = row_start[row], e1 = row_start[row + 1];
    for (int base = e0; base < e1; base += 64) {
        int cnt = min(64, e1 - base);
        int myc = 0; float myw = 0.f;      // inactive lanes: zero weight, col 0
        if (lane < cnt) {
            uint2 s = scolw[base + lane];
            myc = (int)s.x;
            myw = __uint_as_float(s.y);
        }
        // 8-deep unrolled gather; padded slots shuffle from zero-weight lanes.
        // Max shfl index = 8*ceil(cnt/8)-1 <= 63, so no wraparound aliasing.
        for (int i = 0; i < cnt; i += 8) {
            int c[8]; float w[8]; uint32_t q[8];
#pragma unroll
            for (int j = 0; j < 8; ++j) { c[j] = __shfl(myc, i + j); w[j] = __shfl(myw, i + j); }
#pragma unroll
            for (int j = 0; j < 8; ++j) q[j] = h[(size_t)c[j] * 64 + lane];
#pragma unroll
            for (int j = 0; j < 8; ++j) { ax += w[j] * bflo(q[j]); ay += w[j] * bfhi(q[j]); }
        }
    }
    pre[(size_t)row * 64 + lane] = f2bf(ax) | (f2bf(ay) << 16);
}

// ---- out = pre @ W + bias via MFMA bf16 16x16x32 ----
__global__ __launch_bounds__(256) void gemm_kernel(
        const uint16_t* __restrict__ pre, const uint16_t* __restrict__ WT,
        const float* __restrict__ bias, float* __restrict__ out) {
    int wave = threadIdx.x >> 6;
    int lane = threadIdx.x & 63;
    int row0 = blockIdx.x * 64 + wave * 16;
    int m = lane & 15, q = lane >> 4;

    short8_t a[4];
    const uint16_t* arow = pre + (size_t)(row0 + m) * FDIM + q * 8;
#pragma unroll
    for (int t = 0; t < 4; ++t)
        a[t] = *(const short8_t*)(arow + t * 32);

    for (int ct = 0; ct < 8; ++ct) {
        int col0 = ct * 16;
        const uint16_t* brow = WT + (size_t)(col0 + m) * FDIM + q * 8;
        f32x4_t acc = {0.f, 0.f, 0.f, 0.f};
#pragma unroll
        for (int t = 0; t < 4; ++t) {
            short8_t b = *(const short8_t*)(brow + t * 32);
            acc = __builtin_amdgcn_mfma_f32_16x16x32_bf16(a[t], b, acc, 0, 0, 0);
        }
        float bs = bias[col0 + m];
#pragma unroll
        for (int r = 0; r < 4; ++r) {
            int row = row0 + q * 4 + r;
            if (row < N_NODES)
                out[(size_t)row * FDIM + col0 + m] = acc[r] + bs;
        }
    }
}

extern "C" void kernel_launch(void* const* d_in, const int* in_sizes, int n_in,
                              void* d_out, int out_size, void* d_ws, size_t ws_size,
                              hipStream_t stream) {
    const float* x     = (const float*)d_in[0];
    const int*   erows = (const int*)d_in[1];
    const int*   ecols = (const int*)d_in[2];
    const float* evals = (const float*)d_in[3];
    const int*   erels = (const int*)d_in[4];
    const float* relc  = (const float*)d_in[5];
    const float* ck    = (const float*)d_in[6];
    const float* W     = (const float*)d_in[7];
    const float* bias  = (const float*)d_in[8];
    const float* gamma = (const float*)d_in[9];
    const float* beta  = (const float*)d_in[10];
    const float* mean  = (const float*)d_in[11];
    const float* var   = (const float*)d_in[12];
    float* out = (float*)d_out;

    char* wp = (char*)d_ws;
    auto alloc = [&](size_t bytes) {
        char* p = wp;
        wp += (bytes + 255) & ~(size_t)255;
        return (void*)p;
    };
    uint16_t* h      = (uint16_t*)alloc((size_t)N_PAD * FDIM * 2);
    uint16_t* pre    = (uint16_t*)alloc((size_t)N_PAD * FDIM * 2);  // aliased: staging lives here pre-spmm
    uint2* scolw     = (uint2*)alloc((size_t)N_EDGES * 8);
    int* counts      = (int*)alloc((size_t)N_NODES * 4);
    int* row_start   = (int*)alloc((size_t)(N_NODES + 1) * 4);
    int* bcursor     = (int*)alloc((size_t)NBUCK * 4);
    int* bsum        = (int*)alloc(1024 * 4);
    int* boff        = (int*)alloc(1024 * 4);
    uint16_t* WT     = (uint16_t*)alloc(FDIM * FDIM * 2);
    float* scale     = (float*)alloc(FDIM * 4);
    float* shift     = (float*)alloc(FDIM * 4);
    float* rel_inv   = (float*)alloc(256 * 4);
    if ((size_t)(wp - (char*)d_ws) > ws_size) return;

    uint2* staging = (uint2*)pre;   // 12.8MB inside pre's 25.6MB; dead before spmm writes pre

    hipMemsetAsync(counts, 0, (size_t)N_NODES * 4, stream);
    prep_kernel<<<1, 256, 0, stream>>>(gamma, beta, mean, var, relc, W, scale, shift, rel_inv, WT);
    h_kernel<<<(N_NODES * 32) / 256, 256, 0, stream>>>(x, scale, shift, (uint2*)h);
    hist_kernel<<<(N_EDGES + 255) / 256, 256, 0, stream>>>(erows, counts);
    int nb = (N_NODES + SCAN_B - 1) / SCAN_B;
    scan1_kernel<<<nb, SCAN_B, 0, stream>>>(counts, bsum);
    scan2_kernel<<<1, 64, 0, stream>>>(bsum, boff, nb, row_start);
    scan3_kernel<<<nb, SCAN_B, 0, stream>>>(counts, boff, row_start, bcursor);
    partition_kernel<<<(N_EDGES + 255) / 256, 256, 0, stream>>>(erows, ecols, evals, erels,
                                                                rel_inv, bcursor, staging);
    bucket_kernel<<<NBUCK, 256, 0, stream>>>(staging, row_start, scolw);
    spmm_kernel<<<N_NODES / 4, 256, 0, stream>>>((const uint32_t*)h, row_start,
                                                 scolw, ck, (uint32_t*)pre);
    gemm_kernel<<<(N_NODES + 63) / 64, 256, 0, stream>>>(pre, WT, bias, out);
}

// Round 3
// 367.207 us; speedup vs baseline: 1.9171x; 1.9171x over previous
//
#include <hip/hip_runtime.h>
#include <stdint.h>

#define N_NODES 100000
#define N_EDGES 1600000
#define FDIM 128
#define NREL 50
#define BN_EPS 1e-3f
#define N_PAD 100096
#define SCAN_B 1024
#define NBUCK 782          // ceil(N_NODES / 128)
#define EPB 8192           // edges per sort block
#define NBLK 196           // ceil(N_EDGES / EPB)
#define NSEG 4             // ceil(NBLK / 64)

typedef short short8_t __attribute__((ext_vector_type(8)));
typedef float f32x4_t __attribute__((ext_vector_type(4)));

__device__ __forceinline__ uint32_t f2bf(float f) {
    union { float f; uint32_t u; } v; v.f = f;
    uint32_t u = v.u;
    return (u + 0x7FFFu + ((u >> 16) & 1u)) >> 16;   // RNE, inputs finite
}
__device__ __forceinline__ float bflo(uint32_t p) {
    union { uint32_t u; float f; } v; v.u = p << 16; return v.f;
}
__device__ __forceinline__ float bfhi(uint32_t p) {
    union { uint32_t u; float f; } v; v.u = p & 0xFFFF0000u; return v.f;
}

// ---- prep: BN affine params, 1/(relc+1), W^T cast to bf16 ----
__global__ void prep_kernel(const float* __restrict__ gamma, const float* __restrict__ beta,
                            const float* __restrict__ mean, const float* __restrict__ var,
                            const float* __restrict__ relc, const float* __restrict__ W,
                            float* __restrict__ scale, float* __restrict__ shift,
                            float* __restrict__ rel_inv, uint16_t* __restrict__ WT) {
    int t = threadIdx.x;
    if (t < FDIM) {
        float s = gamma[t] * rsqrtf(var[t] + BN_EPS);
        scale[t] = s;
        shift[t] = beta[t] - mean[t] * s;
    }
    if (t < NREL) rel_inv[t] = 1.0f / (relc[t] + 1.0f);
    for (int idx = t; idx < FDIM * FDIM; idx += blockDim.x) {
        int f = idx >> 7, k = idx & 127;
        WT[idx] = (uint16_t)f2bf(W[k * FDIM + f]);   // WT[f][k]
    }
}

// ---- h = BN(x), stored bf16 ----
__global__ void h_kernel(const float* __restrict__ x, const float* __restrict__ scale,
                         const float* __restrict__ shift, uint2* __restrict__ h) {
    int i4 = blockIdx.x * blockDim.x + threadIdx.x;      // 0 .. N*32-1
    if (i4 >= N_NODES * 32) return;
    int cg = (i4 & 31) * 4;
    float4 xv = ((const float4*)x)[i4];
    float4 sc = *(const float4*)(scale + cg);
    float4 sh = *(const float4*)(shift + cg);
    uint2 o;
    o.x = f2bf(xv.x * sc.x + sh.x) | (f2bf(xv.y * sc.y + sh.y) << 16);
    o.y = f2bf(xv.z * sc.z + sh.z) | (f2bf(xv.w * sc.w + sh.w) << 16);
    h[i4] = o;
}

// ---- sort pass 1: per-block bucket histogram (LDS atomics) + global row counts ----
__global__ __launch_bounds__(1024) void sort1_kernel(const int* __restrict__ rows,
                                                     int* __restrict__ counts,
                                                     int* __restrict__ bhist) {
    __shared__ int lh[NBUCK];
    int t = threadIdx.x;
    for (int i = t; i < NBUCK; i += 1024) lh[i] = 0;
    __syncthreads();
    int e0 = blockIdx.x * EPB;
    int e1 = min(e0 + EPB, N_EDGES);
    for (int e = e0 + t; e < e1; e += 1024) {
        int r = rows[e];
        atomicAdd(&counts[r], 1);     // row-level CSR histogram
        atomicAdd(&lh[r >> 7], 1);    // block-local bucket histogram
    }
    __syncthreads();
    for (int i = t; i < NBUCK; i += 1024) bhist[blockIdx.x * NBUCK + i] = lh[i];
}

// ---- row-level prefix (unchanged 3-kernel scan) ----
__global__ void scan1_kernel(const int* __restrict__ counts, int* __restrict__ bsum) {
    __shared__ int sm[SCAN_B];
    int t = threadIdx.x;
    int i = blockIdx.x * SCAN_B + t;
    sm[t] = (i < N_NODES) ? counts[i] : 0;
    __syncthreads();
    for (int s = SCAN_B / 2; s > 0; s >>= 1) {
        if (t < s) sm[t] += sm[t + s];
        __syncthreads();
    }
    if (t == 0) bsum[blockIdx.x] = sm[0];
}

__global__ void scan2_kernel(const int* __restrict__ bsum, int* __restrict__ boff, int nb,
                             int* __restrict__ row_start) {
    if (threadIdx.x == 0) {
        int acc = 0;
        for (int b = 0; b < nb; ++b) { boff[b] = acc; acc += bsum[b]; }
        row_start[N_NODES] = acc;   // sentinel: == N_EDGES
    }
}

__global__ void scan3_kernel(const int* __restrict__ counts, const int* __restrict__ boff,
                             int* __restrict__ row_start) {
    __shared__ int sm[SCAN_B];
    int t = threadIdx.x;
    int i = blockIdx.x * SCAN_B + t;
    int v = (i < N_NODES) ? counts[i] : 0;
    sm[t] = v;
    __syncthreads();
    for (int off = 1; off < SCAN_B; off <<= 1) {
        int xv = 0;
        if (t >= off) xv = sm[t - off];
        __syncthreads();
        sm[t] += xv;
        __syncthreads();
    }
    if (i < N_NODES) row_start[i] = boff[blockIdx.x] + sm[t] - v;   // exclusive
}

// ---- bucket scan: one wave per bucket, prefix over the 196 block counts ----
__global__ __launch_bounds__(256) void bscan_kernel(const int* __restrict__ bhist,
                                                    const int* __restrict__ row_start,
                                                    int* __restrict__ bbase) {
    int wv = (blockIdx.x * 256 + threadIdx.x) >> 6;   // bucket id
    int lane = threadIdx.x & 63;
    if (wv >= NBUCK) return;
    int base = row_start[wv << 7];
    int carry = 0;
#pragma unroll
    for (int seg = 0; seg < NSEG; ++seg) {
        int idx = seg * 64 + lane;
        int v = (idx < NBLK) ? bhist[idx * NBUCK + wv] : 0;
        int s = v;
        for (int d = 1; d < 64; d <<= 1) {
            int u = __shfl_up(s, d);
            if (lane >= d) s += u;
        }
        if (idx < NBLK) bbase[idx * NBUCK + wv] = base + carry + s - v;   // exclusive
        carry += __shfl(s, 63);
    }
}

// ---- sort pass 2: scatter into bucket-sorted staging, LDS cursors only ----
__global__ __launch_bounds__(1024) void sort2_kernel(
        const int* __restrict__ rows, const int* __restrict__ cols,
        const float* __restrict__ vals, const int* __restrict__ rels,
        const float* __restrict__ rel_inv, const int* __restrict__ bbase,
        uint2* __restrict__ staging) {
    __shared__ int lcur[NBUCK];
    int t = threadIdx.x;
    for (int i = t; i < NBUCK; i += 1024) lcur[i] = bbase[blockIdx.x * NBUCK + i];
    __syncthreads();
    int e0 = blockIdx.x * EPB;
    int e1 = min(e0 + EPB, N_EDGES);
    for (int e = e0 + t; e < e1; e += 1024) {
        int r = rows[e];
        float w = vals[e] * rel_inv[rels[e]];
        int p = atomicAdd(&lcur[r >> 7], 1);
        uint2 s;
        s.x = (uint32_t)cols[e] | ((uint32_t)(r & 127) << 20);  // col<2^17, rowlocal<128
        s.y = __float_as_uint(w);
        staging[p] = s;
    }
}

// ---- per-bucket row-level reorder; writes confined to ~16KB windows ----
__global__ __launch_bounds__(256) void bucket_kernel(
        const uint2* __restrict__ staging, const int* __restrict__ row_start,
        uint2* __restrict__ scolw) {
    __shared__ int lcur[128];
    int b = blockIdx.x;
    int r0 = b << 7;
    int nrows = min(128, N_NODES - r0);
    int t = threadIdx.x;
    if (t < nrows) lcur[t] = row_start[r0 + t];
    __syncthreads();
    int e0 = row_start[r0];
    int e1 = row_start[min(r0 + 128, N_NODES)];
    for (int e = e0 + t; e < e1; e += 256) {
        uint2 s = staging[e];
        int rl = (s.x >> 20) & 127;
        int p = atomicAdd(&lcur[rl], 1);
        uint2 o; o.x = s.x & 0xFFFFF; o.y = s.y;
        scolw[p] = o;
    }
}

// ---- pull-mode SpMM + diag: pre[i] = sum w_e h[col_e] + (ck_i+1) h[i] ----
__global__ __launch_bounds__(256) void spmm_kernel(
        const uint32_t* __restrict__ h, const int* __restrict__ row_start,
        const uint2* __restrict__ scolw, const float* __restrict__ ck,
        uint32_t* __restrict__ pre) {
    int row = blockIdx.x * 4 + (threadIdx.x >> 6);
    int lane = threadIdx.x & 63;
    uint32_t p = h[(size_t)row * 64 + lane];
    float coef = ck[row] + 1.0f;
    float ax = coef * bflo(p);
    float ay = coef * bfhi(p);
    int e0 = row_start[row], e1 = row_start[row + 1];
    for (int base = e0; base < e1; base += 64) {
        int cnt = min(64, e1 - base);
        int myc = 0; float myw = 0.f;      // inactive lanes: zero weight, col 0
        if (lane < cnt) {
            uint2 s = scolw[base + lane];
            myc = (int)s.x;
            myw = __uint_as_float(s.y);
        }
        // 8-deep unrolled gather; padded slots shuffle from zero-weight lanes.
        for (int i = 0; i < cnt; i += 8) {
            int c[8]; float w[8]; uint32_t q[8];
#pragma unroll
            for (int j = 0; j < 8; ++j) { c[j] = __shfl(myc, i + j); w[j] = __shfl(myw, i + j); }
#pragma unroll
            for (int j = 0; j < 8; ++j) q[j] = h[(size_t)c[j] * 64 + lane];
#pragma unroll
            for (int j = 0; j < 8; ++j) { ax += w[j] * bflo(q[j]); ay += w[j] * bfhi(q[j]); }
        }
    }
    pre[(size_t)row * 64 + lane] = f2bf(ax) | (f2bf(ay) << 16);
}

// ---- out = pre @ W + bias via MFMA bf16 16x16x32 ----
__global__ __launch_bounds__(256) void gemm_kernel(
        const uint16_t* __restrict__ pre, const uint16_t* __restrict__ WT,
        const float* __restrict__ bias, float* __restrict__ out) {
    int wave = threadIdx.x >> 6;
    int lane = threadIdx.x & 63;
    int row0 = blockIdx.x * 64 + wave * 16;
    int m = lane & 15, q = lane >> 4;

    short8_t a[4];
    const uint16_t* arow = pre + (size_t)(row0 + m) * FDIM + q * 8;
#pragma unroll
    for (int t = 0; t < 4; ++t)
        a[t] = *(const short8_t*)(arow + t * 32);

    for (int ct = 0; ct < 8; ++ct) {
        int col0 = ct * 16;
        const uint16_t* brow = WT + (size_t)(col0 + m) * FDIM + q * 8;
        f32x4_t acc = {0.f, 0.f, 0.f, 0.f};
#pragma unroll
        for (int t = 0; t < 4; ++t) {
            short8_t b = *(const short8_t*)(brow + t * 32);
            acc = __builtin_amdgcn_mfma_f32_16x16x32_bf16(a[t], b, acc, 0, 0, 0);
        }
        float bs = bias[col0 + m];
#pragma unroll
        for (int r = 0; r < 4; ++r) {
            int row = row0 + q * 4 + r;
            if (row < N_NODES)
                out[(size_t)row * FDIM + col0 + m] = acc[r] + bs;
        }
    }
}

extern "C" void kernel_launch(void* const* d_in, const int* in_sizes, int n_in,
                              void* d_out, int out_size, void* d_ws, size_t ws_size,
                              hipStream_t stream) {
    const float* x     = (const float*)d_in[0];
    const int*   erows = (const int*)d_in[1];
    const int*   ecols = (const int*)d_in[2];
    const float* evals = (const float*)d_in[3];
    const int*   erels = (const int*)d_in[4];
    const float* relc  = (const float*)d_in[5];
    const float* ck    = (const float*)d_in[6];
    const float* W     = (const float*)d_in[7];
    const float* bias  = (const float*)d_in[8];
    const float* gamma = (const float*)d_in[9];
    const float* beta  = (const float*)d_in[10];
    const float* mean  = (const float*)d_in[11];
    const float* var   = (const float*)d_in[12];
    float* out = (float*)d_out;

    char* wp = (char*)d_ws;
    auto alloc = [&](size_t bytes) {
        char* p = wp;
        wp += (bytes + 255) & ~(size_t)255;
        return (void*)p;
    };
    uint16_t* h      = (uint16_t*)alloc((size_t)N_PAD * FDIM * 2);
    uint16_t* pre    = (uint16_t*)alloc((size_t)N_PAD * FDIM * 2);  // staging aliased below
    uint2* scolw     = (uint2*)alloc((size_t)N_EDGES * 8);
    int* counts      = (int*)alloc((size_t)N_NODES * 4);
    int* row_start   = (int*)alloc((size_t)(N_NODES + 1) * 4);
    int* bhist       = (int*)alloc((size_t)NBLK * NBUCK * 4);
    int* bbase       = (int*)alloc((size_t)NBLK * NBUCK * 4);
    int* bsum        = (int*)alloc(1024 * 4);
    int* boff        = (int*)alloc(1024 * 4);
    uint16_t* WT     = (uint16_t*)alloc(FDIM * FDIM * 2);
    float* scale     = (float*)alloc(FDIM * 4);
    float* shift     = (float*)alloc(FDIM * 4);
    float* rel_inv   = (float*)alloc(256 * 4);
    if ((size_t)(wp - (char*)d_ws) > ws_size) return;

    uint2* staging = (uint2*)pre;   // 12.8MB inside pre's 25.6MB; dead before spmm writes pre

    hipMemsetAsync(counts, 0, (size_t)N_NODES * 4, stream);
    prep_kernel<<<1, 256, 0, stream>>>(gamma, beta, mean, var, relc, W, scale, shift, rel_inv, WT);
    h_kernel<<<(N_NODES * 32) / 256, 256, 0, stream>>>(x, scale, shift, (uint2*)h);
    sort1_kernel<<<NBLK, 1024, 0, stream>>>(erows, counts, bhist);
    int nb = (N_NODES + SCAN_B - 1) / SCAN_B;
    scan1_kernel<<<nb, SCAN_B, 0, stream>>>(counts, bsum);
    scan2_kernel<<<1, 64, 0, stream>>>(bsum, boff, nb, row_start);
    scan3_kernel<<<nb, SCAN_B, 0, stream>>>(counts, boff, row_start);
    bscan_kernel<<<(NBUCK + 3) / 4, 256, 0, stream>>>(bhist, row_start, bbase);
    sort2_kernel<<<NBLK, 1024, 0, stream>>>(erows, ecols, evals, erels, rel_inv, bbase, staging);
    bucket_kernel<<<NBUCK, 256, 0, stream>>>(staging, row_start, scolw);
    spmm_kernel<<<N_NODES / 4, 256, 0, stream>>>((const uint32_t*)h, row_start,
                                                 scolw, ck, (uint32_t*)pre);
    gemm_kernel<<<(N_NODES + 63) / 64, 256, 0, stream>>>(pre, WT, bias, out);
}

// Round 4
// 301.949 us; speedup vs baseline: 2.3314x; 1.2161x over previous
//
#include <hip/hip_runtime.h>
#include <stdint.h>

#define N_NODES 100000
#define N_EDGES 1600000
#define FDIM 128
#define NREL 50
#define BN_EPS 1e-3f
#define N_PAD 100096
#define NBUCK 782          // ceil(N_NODES / 128)
#define EPB 8192           // edges per sort block
#define NBLK 196           // ceil(N_EDGES / EPB)
#define NSEG 4             // ceil(NBLK / 64)

typedef short short8_t __attribute__((ext_vector_type(8)));
typedef float f32x4_t __attribute__((ext_vector_type(4)));

__device__ __forceinline__ uint32_t f2bf(float f) {
    union { float f; uint32_t u; } v; v.f = f;
    uint32_t u = v.u;
    return (u + 0x7FFFu + ((u >> 16) & 1u)) >> 16;   // RNE, inputs finite
}
__device__ __forceinline__ float bflo(uint32_t p) {
    union { uint32_t u; float f; } v; v.u = p << 16; return v.f;
}
__device__ __forceinline__ float bfhi(uint32_t p) {
    union { uint32_t u; float f; } v; v.u = p & 0xFFFF0000u; return v.f;
}

// ---- prep: BN affine params, 1/(relc+1), W^T cast to bf16 ----
__global__ void prep_kernel(const float* __restrict__ gamma, const float* __restrict__ beta,
                            const float* __restrict__ mean, const float* __restrict__ var,
                            const float* __restrict__ relc, const float* __restrict__ W,
                            float* __restrict__ scale, float* __restrict__ shift,
                            float* __restrict__ rel_inv, uint16_t* __restrict__ WT) {
    int t = threadIdx.x;
    if (t < FDIM) {
        float s = gamma[t] * rsqrtf(var[t] + BN_EPS);
        scale[t] = s;
        shift[t] = beta[t] - mean[t] * s;
    }
    if (t < NREL) rel_inv[t] = 1.0f / (relc[t] + 1.0f);
    for (int idx = t; idx < FDIM * FDIM; idx += blockDim.x) {
        int f = idx >> 7, k = idx & 127;
        WT[idx] = (uint16_t)f2bf(W[k * FDIM + f]);   // WT[f][k]
    }
}

// ---- h = BN(x), stored bf16 ----
__global__ void h_kernel(const float* __restrict__ x, const float* __restrict__ scale,
                         const float* __restrict__ shift, uint2* __restrict__ h) {
    int i4 = blockIdx.x * blockDim.x + threadIdx.x;      // 0 .. N*32-1
    if (i4 >= N_NODES * 32) return;
    int cg = (i4 & 31) * 4;
    float4 xv = ((const float4*)x)[i4];
    float4 sc = *(const float4*)(scale + cg);
    float4 sh = *(const float4*)(shift + cg);
    uint2 o;
    o.x = f2bf(xv.x * sc.x + sh.x) | (f2bf(xv.y * sc.y + sh.y) << 16);
    o.y = f2bf(xv.z * sc.z + sh.z) | (f2bf(xv.w * sc.w + sh.w) << 16);
    h[i4] = o;
}

// ---- sort pass 1: per-block bucket histogram, LDS atomics ONLY ----
__global__ __launch_bounds__(1024) void sort1_kernel(const int* __restrict__ rows,
                                                     int* __restrict__ bhist) {
    __shared__ int lh[NBUCK];
    int t = threadIdx.x;
    for (int i = t; i < NBUCK; i += 1024) lh[i] = 0;
    __syncthreads();
    int e0 = blockIdx.x * EPB;
    int e1 = min(e0 + EPB, N_EDGES);
    for (int e = e0 + t; e < e1; e += 1024)
        atomicAdd(&lh[rows[e] >> 7], 1);
    __syncthreads();
    for (int i = t; i < NBUCK; i += 1024) bhist[blockIdx.x * NBUCK + i] = lh[i];
}

// ---- per-bucket total: one wave per bucket sums its 196 block counts ----
__global__ __launch_bounds__(256) void btot_kernel(const int* __restrict__ bhist,
                                                   int* __restrict__ btot) {
    int wv = (blockIdx.x * 256 + threadIdx.x) >> 6;
    int lane = threadIdx.x & 63;
    if (wv >= NBUCK) return;
    int s = 0;
    for (int idx = lane; idx < NBLK; idx += 64) s += bhist[idx * NBUCK + wv];
    for (int d = 32; d > 0; d >>= 1) s += __shfl_down(s, d);
    if (lane == 0) btot[wv] = s;
}

// ---- bucket prefix: single block scans 782 totals -> bstart (exclusive) ----
__global__ __launch_bounds__(1024) void bprefix_kernel(const int* __restrict__ btot,
                                                       int* __restrict__ bstart,
                                                       int* __restrict__ row_start) {
    __shared__ int sm[1024];
    int t = threadIdx.x;
    int v = (t < NBUCK) ? btot[t] : 0;
    sm[t] = v;
    __syncthreads();
    for (int off = 1; off < 1024; off <<= 1) {
        int xv = 0;
        if (t >= off) xv = sm[t - off];
        __syncthreads();
        sm[t] += xv;
        __syncthreads();
    }
    if (t < NBUCK) bstart[t] = sm[t] - v;   // exclusive
    if (t == 0) {
        bstart[NBUCK] = sm[1023];           // == N_EDGES
        row_start[N_NODES] = sm[1023];      // sentinel for spmm
    }
}

// ---- per-(block,bucket) base: prefix over the 196 block counts ----
__global__ __launch_bounds__(256) void bscan_kernel(const int* __restrict__ bhist,
                                                    const int* __restrict__ bstart,
                                                    int* __restrict__ bbase) {
    int wv = (blockIdx.x * 256 + threadIdx.x) >> 6;   // bucket id
    int lane = threadIdx.x & 63;
    if (wv >= NBUCK) return;
    int base = bstart[wv];
    int carry = 0;
#pragma unroll
    for (int seg = 0; seg < NSEG; ++seg) {
        int idx = seg * 64 + lane;
        int v = (idx < NBLK) ? bhist[idx * NBUCK + wv] : 0;
        int s = v;
        for (int d = 1; d < 64; d <<= 1) {
            int u = __shfl_up(s, d);
            if (lane >= d) s += u;
        }
        if (idx < NBLK) bbase[idx * NBUCK + wv] = base + carry + s - v;   // exclusive
        carry += __shfl(s, 63);
    }
}

// ---- sort pass 2: scatter into bucket-sorted staging, LDS cursors only ----
__global__ __launch_bounds__(1024) void sort2_kernel(
        const int* __restrict__ rows, const int* __restrict__ cols,
        const float* __restrict__ vals, const int* __restrict__ rels,
        const float* __restrict__ rel_inv, const int* __restrict__ bbase,
        uint2* __restrict__ staging) {
    __shared__ int lcur[NBUCK];
    int t = threadIdx.x;
    for (int i = t; i < NBUCK; i += 1024) lcur[i] = bbase[blockIdx.x * NBUCK + i];
    __syncthreads();
    int e0 = blockIdx.x * EPB;
    int e1 = min(e0 + EPB, N_EDGES);
    for (int e = e0 + t; e < e1; e += 1024) {
        int r = rows[e];
        float w = vals[e] * rel_inv[rels[e]];
        int p = atomicAdd(&lcur[r >> 7], 1);
        uint2 s;
        s.x = (uint32_t)cols[e] | ((uint32_t)(r & 127) << 20);  // col<2^17, rowlocal<128
        s.y = __float_as_uint(w);
        staging[p] = s;
    }
}

// ---- per-bucket: LDS row histogram -> row_start + reorder into scolw ----
__global__ __launch_bounds__(256) void bucket_kernel(
        const uint2* __restrict__ staging, const int* __restrict__ bstart,
        int* __restrict__ row_start, uint2* __restrict__ scolw) {
    __shared__ int lh[128];
    __shared__ int sm[128];
    __shared__ int lcur[128];
    int b = blockIdx.x;
    int r0 = b << 7;
    int nrows = min(128, N_NODES - r0);
    int t = threadIdx.x;
    if (t < 128) lh[t] = 0;
    __syncthreads();
    int e0 = bstart[b];
    int e1 = bstart[b + 1];
    for (int e = e0 + t; e < e1; e += 256)
        atomicAdd(&lh[(staging[e].x >> 20) & 127], 1);
    __syncthreads();
    // exclusive scan of lh[0..127]
    int v = (t < 128) ? lh[t] : 0;
    if (t < 128) sm[t] = v;
    __syncthreads();
    for (int off = 1; off < 128; off <<= 1) {
        int xv = 0;
        if (t < 128 && t >= off) xv = sm[t - off];
        __syncthreads();
        if (t < 128) sm[t] += xv;
        __syncthreads();
    }
    if (t < nrows) {
        int rs = e0 + sm[t] - v;   // exclusive
        row_start[r0 + t] = rs;
        lcur[t] = rs;
    }
    __syncthreads();
    for (int e = e0 + t; e < e1; e += 256) {
        uint2 s = staging[e];
        int rl = (s.x >> 20) & 127;
        int p = atomicAdd(&lcur[rl], 1);
        uint2 o; o.x = s.x & 0xFFFFF; o.y = s.y;
        scolw[p] = o;
    }
}

// ---- pull-mode SpMM + diag: pre[i] = sum w_e h[col_e] + (ck_i+1) h[i] ----
__global__ __launch_bounds__(256) void spmm_kernel(
        const uint32_t* __restrict__ h, const int* __restrict__ row_start,
        const uint2* __restrict__ scolw, const float* __restrict__ ck,
        uint32_t* __restrict__ pre) {
    int row = blockIdx.x * 4 + (threadIdx.x >> 6);
    int lane = threadIdx.x & 63;
    uint32_t p = h[(size_t)row * 64 + lane];
    float coef = ck[row] + 1.0f;
    float ax = coef * bflo(p);
    float ay = coef * bfhi(p);
    int e0 = row_start[row], e1 = row_start[row + 1];
    for (int base = e0; base < e1; base += 64) {
        int cnt = min(64, e1 - base);
        int myc = 0; float myw = 0.f;      // inactive lanes: zero weight, col 0
        if (lane < cnt) {
            uint2 s = scolw[base + lane];
            myc = (int)s.x;
            myw = __uint_as_float(s.y);
        }
        // 8-deep unrolled gather; padded slots shuffle from zero-weight lanes.
        for (int i = 0; i < cnt; i += 8) {
            int c[8]; float w[8]; uint32_t q[8];
#pragma unroll
            for (int j = 0; j < 8; ++j) { c[j] = __shfl(myc, i + j); w[j] = __shfl(myw, i + j); }
#pragma unroll
            for (int j = 0; j < 8; ++j) q[j] = h[(size_t)c[j] * 64 + lane];
#pragma unroll
            for (int j = 0; j < 8; ++j) { ax += w[j] * bflo(q[j]); ay += w[j] * bfhi(q[j]); }
        }
    }
    pre[(size_t)row * 64 + lane] = f2bf(ax) | (f2bf(ay) << 16);
}

// ---- out = pre @ W + bias via MFMA bf16 16x16x32 ----
__global__ __launch_bounds__(256) void gemm_kernel(
        const uint16_t* __restrict__ pre, const uint16_t* __restrict__ WT,
        const float* __restrict__ bias, float* __restrict__ out) {
    int wave = threadIdx.x >> 6;
    int lane = threadIdx.x & 63;
    int row0 = blockIdx.x * 64 + wave * 16;
    int m = lane & 15, q = lane >> 4;

    short8_t a[4];
    const uint16_t* arow = pre + (size_t)(row0 + m) * FDIM + q * 8;
#pragma unroll
    for (int t = 0; t < 4; ++t)
        a[t] = *(const short8_t*)(arow + t * 32);

    for (int ct = 0; ct < 8; ++ct) {
        int col0 = ct * 16;
        const uint16_t* brow = WT + (size_t)(col0 + m) * FDIM + q * 8;
        f32x4_t acc = {0.f, 0.f, 0.f, 0.f};
#pragma unroll
        for (int t = 0; t < 4; ++t) {
            short8_t b = *(const short8_t*)(brow + t * 32);
            acc = __builtin_amdgcn_mfma_f32_16x16x32_bf16(a[t], b, acc, 0, 0, 0);
        }
        float bs = bias[col0 + m];
#pragma unroll
        for (int r = 0; r < 4; ++r) {
            int row = row0 + q * 4 + r;
            if (row < N_NODES)
                out[(size_t)row * FDIM + col0 + m] = acc[r] + bs;
        }
    }
}

extern "C" void kernel_launch(void* const* d_in, const int* in_sizes, int n_in,
                              void* d_out, int out_size, void* d_ws, size_t ws_size,
                              hipStream_t stream) {
    const float* x     = (const float*)d_in[0];
    const int*   erows = (const int*)d_in[1];
    const int*   ecols = (const int*)d_in[2];
    const float* evals = (const float*)d_in[3];
    const int*   erels = (const int*)d_in[4];
    const float* relc  = (const float*)d_in[5];
    const float* ck    = (const float*)d_in[6];
    const float* W     = (const float*)d_in[7];
    const float* bias  = (const float*)d_in[8];
    const float* gamma = (const float*)d_in[9];
    const float* beta  = (const float*)d_in[10];
    const float* mean  = (const float*)d_in[11];
    const float* var   = (const float*)d_in[12];
    float* out = (float*)d_out;

    char* wp = (char*)d_ws;
    auto alloc = [&](size_t bytes) {
        char* p = wp;
        wp += (bytes + 255) & ~(size_t)255;
        return (void*)p;
    };
    uint16_t* h      = (uint16_t*)alloc((size_t)N_PAD * FDIM * 2);
    uint16_t* pre    = (uint16_t*)alloc((size_t)N_PAD * FDIM * 2);  // staging aliased below
    uint2* scolw     = (uint2*)alloc((size_t)N_EDGES * 8);
    int* row_start   = (int*)alloc((size_t)(N_NODES + 1) * 4);
    int* bhist       = (int*)alloc((size_t)NBLK * NBUCK * 4);
    int* bbase       = (int*)alloc((size_t)NBLK * NBUCK * 4);
    int* btot        = (int*)alloc((size_t)NBUCK * 4);
    int* bstart      = (int*)alloc((size_t)(NBUCK + 1) * 4);
    uint16_t* WT     = (uint16_t*)alloc(FDIM * FDIM * 2);
    float* scale     = (float*)alloc(FDIM * 4);
    float* shift     = (float*)alloc(FDIM * 4);
    float* rel_inv   = (float*)alloc(256 * 4);
    if ((size_t)(wp - (char*)d_ws) > ws_size) return;

    uint2* staging = (uint2*)pre;   // 12.8MB inside pre's 25.6MB; dead before spmm writes pre

    prep_kernel<<<1, 256, 0, stream>>>(gamma, beta, mean, var, relc, W, scale, shift, rel_inv, WT);
    h_kernel<<<(N_NODES * 32) / 256, 256, 0, stream>>>(x, scale, shift, (uint2*)h);
    sort1_kernel<<<NBLK, 1024, 0, stream>>>(erows, bhist);
    btot_kernel<<<(NBUCK + 3) / 4, 256, 0, stream>>>(bhist, btot);
    bprefix_kernel<<<1, 1024, 0, stream>>>(btot, bstart, row_start);
    bscan_kernel<<<(NBUCK + 3) / 4, 256, 0, stream>>>(bhist, bstart, bbase);
    sort2_kernel<<<NBLK, 1024, 0, stream>>>(erows, ecols, evals, erels, rel_inv, bbase, staging);
    bucket_kernel<<<NBUCK, 256, 0, stream>>>(staging, bstart, row_start, scolw);
    spmm_kernel<<<N_NODES / 4, 256, 0, stream>>>((const uint32_t*)h, row_start,
                                                 scolw, ck, (uint32_t*)pre);
    gemm_kernel<<<(N_NODES + 63) / 64, 256, 0, stream>>>(pre, WT, bias, out);
}